// Round 1
// baseline (367.701 us; speedup 1.0000x reference)
//
#include <hip/hip_runtime.h>
#include <cstdint>
#include <cstddef>

// PTFDecoder: per-joint 4-layer MLP over T=32768 points, B=2, J=14, H=C=128.
// fp16 MFMA (16x16x32) GEMM chain; weights resident in VGPR fragments;
// activations ping-pong through XOR-swizzled LDS tiles of 128 t-columns.

namespace {

constexpr int kJ = 14;
constexpr int kT = 32768;
constexpr int kNIT = 8;                    // 128-col tiles per chunk
constexpr int kSmemBytes = 135168;

using f16x8 = __attribute__((ext_vector_type(8))) _Float16;
using f16x4 = __attribute__((ext_vector_type(4))) _Float16;
using f32x4 = __attribute__((ext_vector_type(4))) float;

__device__ __forceinline__ float f4get(const float4& v, int i) {
    return i == 0 ? v.x : i == 1 ? v.y : i == 2 ? v.z : v.w;
}

__global__ __launch_bounds__(256, 1)
void ptf_kernel(const float* __restrict__ pg,
                const float* __restrict__ cg,
                const float* __restrict__ psg,
                const float* __restrict__ W0g,
                const float* __restrict__ b0g,
                const float* __restrict__ W1g,
                const float* __restrict__ b1g,
                const float* __restrict__ W2g,
                const float* __restrict__ b2g,
                const float* __restrict__ W3g,
                const float* __restrict__ b3g,
                float* __restrict__ outg)
{
    extern __shared__ char smem[];
    char* const buf0 = smem;                     // x tile (even iters)
    char* const buf1 = smem + 32768;             // h0 / h2
    char* const buf2 = smem + 65536;             // h1
    char* const buf3 = smem + 98304;             // x tile (odd iters)
    float* const w0pb = (float*)(smem + 131072); // [128][4] = {w0p0,w0p1,w0p2,b0}
    float* const b12  = (float*)(smem + 133120); // [128][2] = {b1,b2}
    float* const w3s  = (float*)(smem + 134144); // [128] f32
    float* const red  = (float*)(smem + 134656); // [128] f32

    const int tid  = threadIdx.x;
    const int lane = tid & 63;
    const int wid  = tid >> 6;
    const int wr   = wid >> 1;       // M-half (rows 0-63 / 64-127)
    const int wc   = wid & 1;        // N-half (cols 0-63 / 64-127)
    const int lr   = lane & 15;
    const int lg   = lane >> 4;

    // staging decomposition: 32 t-quads x 8 k-chunks(16)
    const int tq  = tid & 31;
    const int kb  = tid >> 5;
    const int rot = (tq >> 1) & 3;   // k-quad rotation to spread LDS write banks

    const int bid   = blockIdx.x;
    const int pair  = bid % 28;
    const int chunk = bid / 28;      // 0..31
    const int j = pair % kJ;
    const int b = pair / kJ;

    // ---------------- weight fragments -> VGPRs ----------------
    // A-frag layout for mfma_f32_16x16x32_f16: row = lane&15, k = (lane>>4)*8 + e
    f16x8 wf0[4][4], wf1[4][4], wf2[4][4];
#pragma unroll
    for (int m = 0; m < 4; ++m) {
        const int r = wr * 64 + m * 16 + lr;
#pragma unroll
        for (int kk = 0; kk < 4; ++kk) {
            const int k = kk * 32 + lg * 8;
            {   // W0 c-part: cols 3..130 (x = [p(3); c(128)])
                const float* s = W0g + (size_t)(j * 128 + r) * 131 + 3 + k;
                f16x8 w;
#pragma unroll
                for (int e = 0; e < 8; ++e) w[e] = (_Float16)s[e];
                wf0[m][kk] = w;
            }
            {
                const float* s = W1g + (size_t)(j * 128 + r) * 128 + k;
                float4 a = *(const float4*)s;
                float4 c4 = *(const float4*)(s + 4);
                f16x8 w;
                w[0] = (_Float16)a.x;  w[1] = (_Float16)a.y;
                w[2] = (_Float16)a.z;  w[3] = (_Float16)a.w;
                w[4] = (_Float16)c4.x; w[5] = (_Float16)c4.y;
                w[6] = (_Float16)c4.z; w[7] = (_Float16)c4.w;
                wf1[m][kk] = w;
            }
            {
                const float* s = W2g + (size_t)(j * 128 + r) * 128 + k;
                float4 a = *(const float4*)s;
                float4 c4 = *(const float4*)(s + 4);
                f16x8 w;
                w[0] = (_Float16)a.x;  w[1] = (_Float16)a.y;
                w[2] = (_Float16)a.z;  w[3] = (_Float16)a.w;
                w[4] = (_Float16)c4.x; w[5] = (_Float16)c4.y;
                w[6] = (_Float16)c4.z; w[7] = (_Float16)c4.w;
                wf2[m][kk] = w;
            }
        }
    }
    if (tid < 128) {
        const int r = tid;
        const size_t jr = (size_t)(j * 128 + r);
        w0pb[r * 4 + 0] = W0g[jr * 131 + 0];
        w0pb[r * 4 + 1] = W0g[jr * 131 + 1];
        w0pb[r * 4 + 2] = W0g[jr * 131 + 2];
        w0pb[r * 4 + 3] = b0g[j * 128 + r];
        b12[r * 2 + 0]  = b1g[j * 128 + r];
        b12[r * 2 + 1]  = b2g[j * 128 + r];
        w3s[r]          = W3g[j * 128 + r];
    }

    // ---------------- helpers ----------------
    auto stage_load2 = [&](int tbase, float4 (&sv)[2][4], int q0) {
#pragma unroll
        for (int qq = 0; qq < 2; ++qq) {
            const int q  = q0 + qq;
            const int k4 = kb * 16 + ((q + rot) & 3) * 4;
#pragma unroll
            for (int rr = 0; rr < 4; ++rr)
                sv[qq][rr] = *(const float4*)(cg + (size_t)(b * 128 + k4 + rr) * kT
                                              + tbase + tq * 4);
        }
    };
    auto stage_store2 = [&](char* dst, const float4 (&sv)[2][4], int q0) {
#pragma unroll
        for (int qq = 0; qq < 2; ++qq) {
            const int q  = q0 + qq;
            const int k4 = kb * 16 + ((q + rot) & 3) * 4;
#pragma unroll
            for (int dt = 0; dt < 4; ++dt) {
                const int t = tq * 4 + dt;
                f16x4 hv;
#pragma unroll
                for (int rr = 0; rr < 4; ++rr) hv[rr] = (_Float16)f4get(sv[qq][rr], dt);
                const uint32_t off = (uint32_t)(t * 256 + k4 * 2)
                                     ^ (uint32_t)((t & 7) << 4);
                *(f16x4*)(dst + off) = hv;
            }
        }
    };
    auto load_pv = [&](int tbase, float (&pv)[4][3]) {
#pragma unroll
        for (int n = 0; n < 4; ++n) {
            const int t = tbase + wc * 64 + n * 16 + lr;
#pragma unroll
            for (int d = 0; d < 3; ++d)
                pv[n][d] = pg[(size_t)(b * 42 + j * 3 + d) * kT + t];
        }
    };
    auto mfma_layer = [&](const f16x8 (&wfl)[4][4], const char* inb, f32x4 (&acc)[4][4]) {
#pragma unroll
        for (int kk = 0; kk < 4; ++kk) {
            f16x8 bf[4];
#pragma unroll
            for (int n = 0; n < 4; ++n) {
                const int t = wc * 64 + n * 16 + lr;
                const uint32_t off = (uint32_t)(t * 256 + kk * 64 + lg * 16)
                                     ^ (uint32_t)((t & 7) << 4);
                bf[n] = *(const f16x8*)(inb + off);
            }
#pragma unroll
            for (int m = 0; m < 4; ++m)
#pragma unroll
                for (int n = 0; n < 4; ++n)
                    acc[m][n] = __builtin_amdgcn_mfma_f32_16x16x32_f16(
                        wfl[m][kk], bf[n], acc[m][n], 0, 0, 0);
        }
    };
    auto store_relu = [&](char* outb, const f32x4 (&acc)[4][4]) {
#pragma unroll
        for (int m = 0; m < 4; ++m) {
            const int hb = wr * 64 + m * 16 + lg * 4;
#pragma unroll
            for (int n = 0; n < 4; ++n) {
                const int t = wc * 64 + n * 16 + lr;
                f16x4 hv;
#pragma unroll
                for (int i = 0; i < 4; ++i)
                    hv[i] = (_Float16)fmaxf(acc[m][n][i], 0.0f);
                const uint32_t off = (uint32_t)(t * 256 + hb * 2)
                                     ^ (uint32_t)((t & 7) << 4);
                *(f16x4*)(outb + off) = hv;
            }
        }
    };

    // ---------------- prologue: stage tile 0 ----------------
    const int tchunk0 = chunk * (kNIT * 128);
    float pv[4][3];
    {
        float4 svA[2][4], svB[2][4];
        stage_load2(tchunk0, svA, 0);
        stage_load2(tchunk0, svB, 2);
        stage_store2(buf0, svA, 0);
        stage_store2(buf0, svB, 2);
        load_pv(tchunk0, pv);
    }
    __syncthreads();

    // ---------------- main loop over 128-col tiles ----------------
    for (int it = 0; it < kNIT; ++it) {
        const int t0 = tchunk0 + it * 128;
        const char* X = (it & 1) ? buf3 : buf0;
        char* Xn      = (it & 1) ? buf0 : buf3;
        const bool more = (it + 1 < kNIT);

        float4 svA[2][4];
        if (more) stage_load2(t0 + 128, svA, 0);

        // ---- layer 0: acc init = b0 + W0p*p, then K=128 over c
        f32x4 acc[4][4];
#pragma unroll
        for (int m = 0; m < 4; ++m)
#pragma unroll
            for (int i = 0; i < 4; ++i) {
                const int r = wr * 64 + m * 16 + lg * 4 + i;
                const float4 wb = *(const float4*)(w0pb + r * 4);
#pragma unroll
                for (int n = 0; n < 4; ++n)
                    acc[m][n][i] = wb.w + wb.x * pv[n][0] + wb.y * pv[n][1]
                                   + wb.z * pv[n][2];
            }
        mfma_layer(wf0, X, acc);
        store_relu(buf1, acc);
        __syncthreads();

        float4 svB[2][4];
        if (more) {
            stage_store2(Xn, svA, 0);
            stage_load2(t0 + 128, svB, 2);
        }
        float pvN[4][3];
        if (more) load_pv(t0 + 128, pvN);

        // ---- layer 1
#pragma unroll
        for (int m = 0; m < 4; ++m)
#pragma unroll
            for (int i = 0; i < 4; ++i) {
                const int r = wr * 64 + m * 16 + lg * 4 + i;
                const float bv = b12[r * 2 + 0];
#pragma unroll
                for (int n = 0; n < 4; ++n) acc[m][n][i] = bv;
            }
        mfma_layer(wf1, buf1, acc);
        store_relu(buf2, acc);
        __syncthreads();

        if (more) stage_store2(Xn, svB, 2);

        // ---- layer 2
#pragma unroll
        for (int m = 0; m < 4; ++m)
#pragma unroll
            for (int i = 0; i < 4; ++i) {
                const int r = wr * 64 + m * 16 + lg * 4 + i;
                const float bv = b12[r * 2 + 1];
#pragma unroll
                for (int n = 0; n < 4; ++n) acc[m][n][i] = bv;
            }
        mfma_layer(wf2, buf2, acc);
        store_relu(buf1, acc);
        __syncthreads();

        // ---- epilogue: o = W3 . h2 + b3 ; out += o*ps/J
        {
            const int th   = tid & 127;
            const int half = tid >> 7;
            float sum = 0.f;
#pragma unroll
            for (int i = 0; i < 8; ++i) {
                const uint32_t off = (uint32_t)(th * 256 + half * 128 + i * 16)
                                     ^ (uint32_t)((th & 7) << 4);
                const f16x8 hv = *(const f16x8*)(buf1 + off);
#pragma unroll
                for (int e = 0; e < 8; ++e)
                    sum += (float)hv[e] * w3s[half * 64 + i * 8 + e];
            }
            if (half) red[th] = sum;
            __syncthreads();
            if (!half) {
                const float o = sum + red[th] + b3g[j];
                const float res = o * psg[(size_t)(b * kJ + j) * kT + t0 + th]
                                  * (1.0f / 14.0f);
                atomicAdd(outg + (size_t)b * kT + t0 + th, res);
            }
        }
#pragma unroll
        for (int n = 0; n < 4; ++n)
#pragma unroll
            for (int d = 0; d < 3; ++d) pv[n][d] = pvN[n][d];
        __syncthreads();
    }
}

} // namespace

extern "C" void kernel_launch(void* const* d_in, const int* in_sizes, int n_in,
                              void* d_out, int out_size, void* d_ws, size_t ws_size,
                              hipStream_t stream) {
    (void)in_sizes; (void)n_in; (void)d_ws; (void)ws_size; (void)out_size;
    const float* pg  = (const float*)d_in[0];
    // d_in[1] = z (unused by the reference)
    const float* cg  = (const float*)d_in[2];
    const float* psg = (const float*)d_in[3];
    const float* W0g = (const float*)d_in[4];
    const float* b0g = (const float*)d_in[5];
    const float* W1g = (const float*)d_in[6];
    const float* b1g = (const float*)d_in[7];
    const float* W2g = (const float*)d_in[8];
    const float* b2g = (const float*)d_in[9];
    const float* W3g = (const float*)d_in[10];
    const float* b3g = (const float*)d_in[11];
    float* outg = (float*)d_out;

    hipMemsetAsync(d_out, 0, (size_t)2 * kT * sizeof(float), stream);
    hipFuncSetAttribute(reinterpret_cast<const void*>(&ptf_kernel),
                        hipFuncAttributeMaxDynamicSharedMemorySize, kSmemBytes);
    ptf_kernel<<<dim3(896), dim3(256), kSmemBytes, stream>>>(
        pg, cg, psg, W0g, b0g, W1g, b1g, W2g, b2g, W3g, b3g, outg);
}

// Round 2
// 285.892 us; speedup vs baseline: 1.2862x; 1.2862x over previous
//
#include <hip/hip_runtime.h>
#include <cstdint>
#include <cstddef>

// PTFDecoder round 2: 64-col tiles, 2 blocks/CU (69 KB LDS), 4M x 1N waves
// (wave = 32 rows x 64 cols -> 96 VGPR weight frags), in-register W3 epilogue,
// 3 barriers/iter. fp16 MFMA 16x16x32, fp32 accumulate.

namespace {

constexpr int kJ = 14;
constexpr int kT = 32768;
constexpr int kNIT = 8;                   // 64-col tiles per block
constexpr int kChunkCols = kNIT * 64;     // 512
constexpr int kSmemBytes = 70656;

using f16x8 = __attribute__((ext_vector_type(8))) _Float16;
using f16x4 = __attribute__((ext_vector_type(4))) _Float16;
using f32x4 = __attribute__((ext_vector_type(4))) float;

__device__ __forceinline__ float f4get(const float4& v, int i) {
    return i == 0 ? v.x : i == 1 ? v.y : i == 2 ? v.z : v.w;
}

__global__ __launch_bounds__(256, 2)
void ptf_kernel(const float* __restrict__ pg,
                const float* __restrict__ cg,
                const float* __restrict__ psg,
                const float* __restrict__ W0g,
                const float* __restrict__ b0g,
                const float* __restrict__ W1g,
                const float* __restrict__ b1g,
                const float* __restrict__ W2g,
                const float* __restrict__ b2g,
                const float* __restrict__ W3g,
                const float* __restrict__ b3g,
                float* __restrict__ outg)
{
    extern __shared__ char smem[];
    char* const X0  = smem;                      // 16 KB fp16 [t][k] swizzled
    char* const X1  = smem + 16384;
    char* const H0  = smem + 32768;
    char* const H1  = smem + 49152;
    float* const w0pb = (float*)(smem + 65536);  // [128][4] {w0p0,w0p1,w0p2,b0}
    float* const b12  = (float*)(smem + 67584);  // [128][2] {b1,b2}
    float* const redf = (float*)(smem + 68608);  // [2][4][64] f32

    const int tid  = threadIdx.x;
    const int lane = tid & 63;
    const int w    = tid >> 6;      // wave 0..3 owns rows 32w..32w+31
    const int lr   = lane & 15;
    const int lg   = lane >> 4;

    // staging decomposition: 16 t-quads x 16 k-octets
    const int tq = tid & 15;
    const int kb = tid >> 4;

    const int bid   = blockIdx.x;
    const int pair  = bid % 28;
    const int chunk = bid / 28;     // 0..63
    const int j = pair % kJ;
    const int b = pair / kJ;
    const int t0c = chunk * kChunkCols;

    // ---------------- weight fragments -> VGPRs ----------------
    // A-frag (16x16x32 f16): row = lane&15, k = (lane>>4)*8 + e
    f16x8 wf0[2][4], wf1[2][4], wf2[2][4];
#pragma unroll
    for (int m = 0; m < 2; ++m) {
        const int r = w * 32 + m * 16 + lr;
#pragma unroll
        for (int kk = 0; kk < 4; ++kk) {
            const int k = kk * 32 + lg * 8;
            {   // W0 c-part: cols 3..130 (x = [p(3); c(128)]), stride 131
                const float* s = W0g + (size_t)(j * 128 + r) * 131 + 3 + k;
                f16x8 wv;
#pragma unroll
                for (int e = 0; e < 8; ++e) wv[e] = (_Float16)s[e];
                wf0[m][kk] = wv;
            }
            {
                const float* s = W1g + (size_t)(j * 128 + r) * 128 + k;
                float4 a = *(const float4*)s;
                float4 c4 = *(const float4*)(s + 4);
                f16x8 wv;
                wv[0] = (_Float16)a.x;  wv[1] = (_Float16)a.y;
                wv[2] = (_Float16)a.z;  wv[3] = (_Float16)a.w;
                wv[4] = (_Float16)c4.x; wv[5] = (_Float16)c4.y;
                wv[6] = (_Float16)c4.z; wv[7] = (_Float16)c4.w;
                wf1[m][kk] = wv;
            }
            {
                const float* s = W2g + (size_t)(j * 128 + r) * 128 + k;
                float4 a = *(const float4*)s;
                float4 c4 = *(const float4*)(s + 4);
                f16x8 wv;
                wv[0] = (_Float16)a.x;  wv[1] = (_Float16)a.y;
                wv[2] = (_Float16)a.z;  wv[3] = (_Float16)a.w;
                wv[4] = (_Float16)c4.x; wv[5] = (_Float16)c4.y;
                wv[6] = (_Float16)c4.z; wv[7] = (_Float16)c4.w;
                wf2[m][kk] = wv;
            }
        }
    }
    // W3 per-lane values for in-register epilogue: rows w*32+m*16+lg*4+i
    float w3v[8];
#pragma unroll
    for (int m = 0; m < 2; ++m)
#pragma unroll
        for (int i = 0; i < 4; ++i)
            w3v[m * 4 + i] = W3g[j * 128 + w * 32 + m * 16 + lg * 4 + i];

    if (tid < 128) {
        const int r = tid;
        const size_t jr = (size_t)(j * 128 + r);
        w0pb[r * 4 + 0] = W0g[jr * 131 + 0];
        w0pb[r * 4 + 1] = W0g[jr * 131 + 1];
        w0pb[r * 4 + 2] = W0g[jr * 131 + 2];
        w0pb[r * 4 + 3] = b0g[j * 128 + r];
        b12[r * 2 + 0]  = b1g[j * 128 + r];
        b12[r * 2 + 1]  = b2g[j * 128 + r];
    }
    const float b3v = b3g[j];

    // ---------------- helpers ----------------
    auto stage_issue = [&](int tbase, float4 (&sv)[8]) {
#pragma unroll
        for (int e = 0; e < 8; ++e) {
            const int k = kb * 8 + e;
            sv[e] = *(const float4*)(cg + (size_t)(b * 128 + k) * kT
                                     + tbase + tq * 4);
        }
    };
    auto stage_write = [&](char* dst, const float4 (&sv)[8]) {
#pragma unroll
        for (int dt = 0; dt < 4; ++dt) {
            const int t = tq * 4 + dt;
            f16x8 hv;
#pragma unroll
            for (int e = 0; e < 8; ++e) hv[e] = (_Float16)f4get(sv[e], dt);
            const uint32_t off = (uint32_t)(t * 256 + kb * 16)
                                 ^ (uint32_t)((t & 7) << 4);
            *(f16x8*)(dst + off) = hv;
        }
    };
    auto load_pv = [&](int tbase, float (&pv)[4][3]) {
#pragma unroll
        for (int n = 0; n < 4; ++n) {
            const int t = tbase + n * 16 + lr;
#pragma unroll
            for (int d = 0; d < 3; ++d)
                pv[n][d] = pg[(size_t)(b * 42 + j * 3 + d) * kT + t];
        }
    };
    auto mfma_layer = [&](const f16x8 (&wfl)[2][4], const char* inb,
                          f32x4 (&acc)[2][4]) {
#pragma unroll
        for (int kk = 0; kk < 4; ++kk) {
            f16x8 bf[4];
#pragma unroll
            for (int n = 0; n < 4; ++n) {
                const int t = n * 16 + lr;
                const uint32_t off = (uint32_t)(t * 256 + kk * 64 + lg * 16)
                                     ^ (uint32_t)((t & 7) << 4);
                bf[n] = *(const f16x8*)(inb + off);
            }
#pragma unroll
            for (int m = 0; m < 2; ++m)
#pragma unroll
                for (int n = 0; n < 4; ++n)
                    acc[m][n] = __builtin_amdgcn_mfma_f32_16x16x32_f16(
                        wfl[m][kk], bf[n], acc[m][n], 0, 0, 0);
        }
    };
    auto store_relu = [&](char* outb, const f32x4 (&acc)[2][4]) {
#pragma unroll
        for (int m = 0; m < 2; ++m) {
            const int hb = w * 32 + m * 16 + lg * 4;
#pragma unroll
            for (int n = 0; n < 4; ++n) {
                const int t = n * 16 + lr;
                f16x4 hv;
#pragma unroll
                for (int i = 0; i < 4; ++i)
                    hv[i] = (_Float16)fmaxf(acc[m][n][i], 0.0f);
                const uint32_t off = (uint32_t)(t * 256 + hb * 2)
                                     ^ (uint32_t)((t & 7) << 4);
                *(f16x4*)(outb + off) = hv;
            }
        }
    };

    // ---------------- prologue ----------------
    float pv[4][3];
    {
        float4 sv[8];
        stage_issue(t0c, sv);
        load_pv(t0c, pv);
        stage_write(X0, sv);
    }
    __syncthreads();

    // ---------------- main loop ----------------
    for (int it = 0; it < kNIT; ++it) {
        const int t0 = t0c + it * 64;
        char* Xc = (it & 1) ? X1 : X0;
        char* Xn = (it & 1) ? X0 : X1;
        const bool more = (it + 1 < kNIT);

        // drain epilogue of previous iter (red[(it-1)&1] ready after last barrier)
        if (it > 0 && tid < 64) {
            const int p = (it - 1) & 1;
            const int t = t0 - 64 + tid;
            float s = redf[(p * 4 + 0) * 64 + tid] + redf[(p * 4 + 1) * 64 + tid]
                    + redf[(p * 4 + 2) * 64 + tid] + redf[(p * 4 + 3) * 64 + tid];
            const float o = s + b3v;
            atomicAdd(outg + (size_t)b * kT + t,
                      o * psg[(size_t)(b * kJ + j) * kT + t] * (1.0f / 14.0f));
        }

        float4 sv[8];
        if (more) stage_issue(t0 + 64, sv);

        // ---- layer 0: acc init = b0 + W0p*p
        f32x4 acc[2][4];
#pragma unroll
        for (int m = 0; m < 2; ++m)
#pragma unroll
            for (int i = 0; i < 4; ++i) {
                const int r = w * 32 + m * 16 + lg * 4 + i;
                const float4 wb = *(const float4*)(w0pb + r * 4);
#pragma unroll
                for (int n = 0; n < 4; ++n)
                    acc[m][n][i] = wb.w + wb.x * pv[n][0] + wb.y * pv[n][1]
                                   + wb.z * pv[n][2];
            }
        mfma_layer(wf0, Xc, acc);
        store_relu(H0, acc);
        float pvN[4][3];
        if (more) load_pv(t0 + 64, pvN);
        __syncthreads();   // B1: H0 ready

        // ---- layer 1
#pragma unroll
        for (int m = 0; m < 2; ++m)
#pragma unroll
            for (int i = 0; i < 4; ++i) {
                const float bv = b12[(w * 32 + m * 16 + lg * 4 + i) * 2 + 0];
#pragma unroll
                for (int n = 0; n < 4; ++n) acc[m][n][i] = bv;
            }
        mfma_layer(wf1, H0, acc);
        store_relu(H1, acc);
        if (more) stage_write(Xn, sv);
        __syncthreads();   // B2: H1 ready, Xnext staged

        // ---- layer 2 + in-register W3 epilogue
#pragma unroll
        for (int m = 0; m < 2; ++m)
#pragma unroll
            for (int i = 0; i < 4; ++i) {
                const float bv = b12[(w * 32 + m * 16 + lg * 4 + i) * 2 + 1];
#pragma unroll
                for (int n = 0; n < 4; ++n) acc[m][n][i] = bv;
            }
        mfma_layer(wf2, H1, acc);

        {
            const int p = it & 1;
            float part[4];
#pragma unroll
            for (int n = 0; n < 4; ++n) {
                float s = 0.f;
#pragma unroll
                for (int m = 0; m < 2; ++m)
#pragma unroll
                    for (int i = 0; i < 4; ++i)
                        s += fmaxf(acc[m][n][i], 0.0f) * w3v[m * 4 + i];
                s += __shfl_xor(s, 16);
                s += __shfl_xor(s, 32);
                part[n] = s;
            }
            if (lg == 0) {
#pragma unroll
                for (int n = 0; n < 4; ++n)
                    redf[(p * 4 + w) * 64 + n * 16 + lr] = part[n];
            }
        }
#pragma unroll
        for (int n = 0; n < 4; ++n)
#pragma unroll
            for (int d = 0; d < 3; ++d) pv[n][d] = pvN[n][d];
        __syncthreads();   // B3: red ready, buffers free
    }

    // tail drain (it = kNIT-1)
    if (tid < 64) {
        const int p = (kNIT - 1) & 1;
        const int t = t0c + (kNIT - 1) * 64 + tid;
        float s = redf[(p * 4 + 0) * 64 + tid] + redf[(p * 4 + 1) * 64 + tid]
                + redf[(p * 4 + 2) * 64 + tid] + redf[(p * 4 + 3) * 64 + tid];
        const float o = s + b3v;
        atomicAdd(outg + (size_t)b * kT + t,
                  o * psg[(size_t)(b * kJ + j) * kT + t] * (1.0f / 14.0f));
    }
}

} // namespace

extern "C" void kernel_launch(void* const* d_in, const int* in_sizes, int n_in,
                              void* d_out, int out_size, void* d_ws, size_t ws_size,
                              hipStream_t stream) {
    (void)in_sizes; (void)n_in; (void)d_ws; (void)ws_size; (void)out_size;
    const float* pg  = (const float*)d_in[0];
    // d_in[1] = z (unused by the reference)
    const float* cg  = (const float*)d_in[2];
    const float* psg = (const float*)d_in[3];
    const float* W0g = (const float*)d_in[4];
    const float* b0g = (const float*)d_in[5];
    const float* W1g = (const float*)d_in[6];
    const float* b1g = (const float*)d_in[7];
    const float* W2g = (const float*)d_in[8];
    const float* b2g = (const float*)d_in[9];
    const float* W3g = (const float*)d_in[10];
    const float* b3g = (const float*)d_in[11];
    float* outg = (float*)d_out;

    hipMemsetAsync(d_out, 0, (size_t)2 * kT * sizeof(float), stream);
    hipFuncSetAttribute(reinterpret_cast<const void*>(&ptf_kernel),
                        hipFuncAttributeMaxDynamicSharedMemorySize, kSmemBytes);
    ptf_kernel<<<dim3(1792), dim3(256), kSmemBytes, stream>>>(
        pg, cg, psg, W0g, b0g, W1g, b1g, W2g, b2g, W3g, b3g, outg);
}